// Round 1
// baseline (38.186 us; speedup 1.0000x reference)
//
#include <hip/hip_runtime.h>

// RandomCrop (integer shift with zero padding):
//   out[n,c,i,j] = in[n,c, i+sy, j+sx] if in-range else 0
//   sx = shifts[n,0]-8 (x / width), sy = shifts[n,1]-8 (y / height)
// N=128, C=3, H=256, W=256, fp32. Pure memory-bound shifted copy.

#define MAXPIX 8
#define W 256
#define H 256
#define CCH 3

__global__ __launch_bounds__(256) void shift_kernel(
    const float* __restrict__ in,
    const int* __restrict__ shifts,
    float* __restrict__ out,
    int total_rows)   // N*C*H
{
    // One 64-lane wave per output row: 256 floats = 64 lanes x float4.
    const int lane = threadIdx.x & 63;
    const int wave_in_block = threadIdx.x >> 6;        // 0..3
    const int rows_per_block = 256 / 64;               // 4
    int row = blockIdx.x * rows_per_block + wave_in_block;
    const int row_stride = gridDim.x * rows_per_block;

    for (; row < total_rows; row += row_stride) {
        const int i  = row & (H - 1);                  // H = 256 (pow2)
        const int nc = row >> 8;                       // n*C + c
        const int n  = nc / CCH;                       // compiler: magic-mul

        const int sx = shifts[2 * n]     - MAXPIX;     // x shift (width)
        const int sy = shifts[2 * n + 1] - MAXPIX;     // y shift (height)

        const int src_y = i + sy;
        float4 v = {0.f, 0.f, 0.f, 0.f};
        if ((unsigned)src_y < (unsigned)H) {
            const float* __restrict__ src =
                in + ((long)nc * H + src_y) * W;
            const int j0 = (lane << 2) + sx;           // source x of v.x
            // 4 scalar loads; lanes overlap cache lines -> L1 absorbs,
            // HBM traffic stays ~1x. Predicated zero at the x fringe.
            v.x = ((unsigned)(j0 + 0) < (unsigned)W) ? src[j0 + 0] : 0.f;
            v.y = ((unsigned)(j0 + 1) < (unsigned)W) ? src[j0 + 1] : 0.f;
            v.z = ((unsigned)(j0 + 2) < (unsigned)W) ? src[j0 + 2] : 0.f;
            v.w = ((unsigned)(j0 + 3) < (unsigned)W) ? src[j0 + 3] : 0.f;
        }
        // Aligned, fully coalesced 16B store (row base is 1KiB aligned).
        *reinterpret_cast<float4*>(out + (long)row * W + (lane << 2)) = v;
    }
}

extern "C" void kernel_launch(void* const* d_in, const int* in_sizes, int n_in,
                              void* d_out, int out_size, void* d_ws, size_t ws_size,
                              hipStream_t stream) {
    const float* in     = (const float*)d_in[0];
    const int*   shifts = (const int*)d_in[1];
    float*       out    = (float*)d_out;

    const int total_rows = out_size / W;               // N*C*H = 98304

    // Memory-bound: cap grid ~2048 blocks (8 blocks/CU), grid-stride the rest.
    const int rows_per_block = 4;                      // 256 threads / 64 lanes
    int blocks = (total_rows + rows_per_block - 1) / rows_per_block;
    if (blocks > 2048) blocks = 2048;

    shift_kernel<<<dim3(blocks), dim3(256), 0, stream>>>(in, shifts, out, total_rows);
}

// Round 3
// 36.960 us; speedup vs baseline: 1.0332x; 1.0332x over previous
//
#include <hip/hip_runtime.h>

// RandomCrop (integer shift with zero padding):
//   out[n,c,i,j] = in[n,c, i+sy, j+sx] if in-range else 0
//   sx = shifts[n,0]-8, sy = shifts[n,1]-8. N=128,C=3,H=256,W=256 fp32.
// Pure shifted copy: latency-bound fix = max independent loads per wave,
// branchless (clamped addresses + cndmask zeroing), nontemporal stores.

#define MAXPIX 8
#define W 256
#define H 256
#define CCH 3

typedef float f32x4 __attribute__((ext_vector_type(4)));  // clang vector: ok for nontemporal builtin

__global__ __launch_bounds__(256) void shift_kernel(
    const float* __restrict__ in,
    const int* __restrict__ shifts,
    float* __restrict__ out,
    int total_rows)   // N*C*H = 98304
{
    const int lane = threadIdx.x & 63;
    const int wid  = threadIdx.x >> 6;             // wave in block, 0..3
    constexpr int R = 4;                           // rows per wave
    const int row0 = (blockIdx.x * 4 + wid) * R;   // exact-cover grid, no loop
    if (row0 >= total_rows) return;

    f32x4 v[R];

    #pragma unroll
    for (int r = 0; r < R; ++r) {
        int rr = row0 + r;
        rr = min(rr, total_rows - 1);              // load-side clamp (tail safety)
        const int i  = rr & (H - 1);
        const int nc = rr >> 8;                    // n*C + c
        int n = nc / CCH;                          // magic-mul
        n = __builtin_amdgcn_readfirstlane(n);     // uniform -> s_load of shifts

        const int sx = shifts[2 * n]     - MAXPIX;
        const int sy = shifts[2 * n + 1] - MAXPIX;

        const int  syr = i + sy;
        const int  syc = min(max(syr, 0), H - 1);  // clamped: load always in-bounds
        const bool vy  = (unsigned)syr < (unsigned)H;

        const float* __restrict__ src = in + ((long)nc * H + syc) * W;
        const int j0 = (lane << 2) + sx;

        // All loads unconditional (clamped addr), zeroed by cndmask after.
        const int jc0 = min(max(j0 + 0, 0), W - 1);
        const int jc1 = min(max(j0 + 1, 0), W - 1);
        const int jc2 = min(max(j0 + 2, 0), W - 1);
        const int jc3 = min(max(j0 + 3, 0), W - 1);
        float x0 = src[jc0], x1 = src[jc1], x2 = src[jc2], x3 = src[jc3];

        v[r].x = (vy && (unsigned)(j0 + 0) < (unsigned)W) ? x0 : 0.f;
        v[r].y = (vy && (unsigned)(j0 + 1) < (unsigned)W) ? x1 : 0.f;
        v[r].z = (vy && (unsigned)(j0 + 2) < (unsigned)W) ? x2 : 0.f;
        v[r].w = (vy && (unsigned)(j0 + 3) < (unsigned)W) ? x3 : 0.f;
    }

    #pragma unroll
    for (int r = 0; r < R; ++r) {
        const int rr = row0 + r;
        if (rr < total_rows) {
            // Write-once streaming output: nontemporal, don't pollute L2/L3.
            __builtin_nontemporal_store(v[r],
                reinterpret_cast<f32x4*>(out + (long)rr * W + (lane << 2)));
        }
    }
}

extern "C" void kernel_launch(void* const* d_in, const int* in_sizes, int n_in,
                              void* d_out, int out_size, void* d_ws, size_t ws_size,
                              hipStream_t stream) {
    const float* in     = (const float*)d_in[0];
    const int*   shifts = (const int*)d_in[1];
    float*       out    = (float*)d_out;

    const int total_rows = out_size / W;           // 98304

    // Exact cover: each block = 4 waves x 4 rows = 16 rows.
    const int rows_per_block = 16;
    const int blocks = (total_rows + rows_per_block - 1) / rows_per_block;  // 6144

    shift_kernel<<<dim3(blocks), dim3(256), 0, stream>>>(in, shifts, out, total_rows);
}